// Round 4
// baseline (758.078 us; speedup 1.0000x reference)
//
#include <hip/hip_runtime.h>
#include <hip/hip_bf16.h>
#include <math.h>

#define H     1024
#define FFN   4096
#define NE    8
#define TOK   2048
#define PAIRS (TOK*2)
#define BM    128
#define BK    32
#define ROWCAP (PAIRS + NE*BM)   /* 5120 worst-case padded rows */
#define MAXTILES (ROWCAP/BM)     /* 40 */

typedef unsigned short u16;
typedef __attribute__((ext_vector_type(8))) __bf16 bf16x8;
typedef __attribute__((ext_vector_type(4))) float  f32x4;

// hardware v_cvt_pk_bf16_f32: 2 floats -> packed 2xbf16 in one inst
__device__ __forceinline__ unsigned cvt2(float a, float b) {
    __hip_bfloat162 h = __float22bfloat162_rn(float2{a, b});
    unsigned u;
    __builtin_memcpy(&u, &h, 4);
    return u;
}

#define GLD16(gp, lp) __builtin_amdgcn_global_load_lds( \
    (const __attribute__((address_space(1))) void*)(gp), \
    (__attribute__((address_space(3))) void*)(lp), 16, 0, 0)

// ---------------- kernel 0: convert weights fp32 -> bf16 (HBM-bound) ----------------
// 100.66M elems, 8 per thread: 12,582,912 threads = 49152 blocks x 256 exactly.
__global__ __launch_bounds__(256) void k_cvtw(const float4* __restrict__ w13,
                                              const float4* __restrict__ w2,
                                              uint4* __restrict__ o13,
                                              uint4* __restrict__ o2) {
    size_t i = (size_t)blockIdx.x * 256 + threadIdx.x;     // one per 8 floats
    const size_t N13 = (size_t)NE * 2 * FFN * H / 8;       // 8,388,608
    const float4* src; uint4* dst; size_t j;
    if (i < N13) { src = w13; dst = o13; j = i; }
    else         { src = w2;  dst = o2;  j = i - N13; }
    float4 a = src[2 * j], b = src[2 * j + 1];
    uint4 o = { cvt2(a.x, a.y), cvt2(a.z, a.w), cvt2(b.x, b.y), cvt2(b.z, b.w) };
    dst[j] = o;
}

// ---------------- kernel 1: init counts ----------------
__global__ void k_init(int* counts) {
    if (threadIdx.x < NE) counts[threadIdx.x] = 0;
}

// ---------------- kernel 2: router ----------------
__global__ void k_router(const float* __restrict__ x, const float* __restrict__ gw,
                         float* __restrict__ logits, int* counts,
                         int* __restrict__ sel, int* __restrict__ posn, float* __restrict__ wgt) {
    int lane = threadIdx.x & 63;
    int t = blockIdx.x * 4 + (threadIdx.x >> 6);
    float p[NE];
#pragma unroll
    for (int e = 0; e < NE; e++) p[e] = 0.f;
    for (int j = 0; j < H / 64; j++) {
        int h = lane + j * 64;
        float xv = x[(size_t)t * H + h];
#pragma unroll
        for (int e = 0; e < NE; e++) p[e] = fmaf(xv, gw[e * H + h], p[e]);
    }
#pragma unroll
    for (int off = 32; off; off >>= 1)
#pragma unroll
        for (int e = 0; e < NE; e++) p[e] += __shfl_xor(p[e], off, 64);
    if (lane == 0) {
        float mx = p[0];
#pragma unroll
        for (int e = 1; e < NE; e++) mx = fmaxf(mx, p[e]);
        float pe[NE];
#pragma unroll
        for (int e = 0; e < NE; e++) pe[e] = __expf(p[e] - mx);
        int i0 = 0;
#pragma unroll
        for (int e = 1; e < NE; e++) if (pe[e] > pe[i0]) i0 = e;
        int i1 = (i0 == 0) ? 1 : 0;
#pragma unroll
        for (int e = 0; e < NE; e++) if (e != i1 && e != i0 && pe[e] > pe[i1]) i1 = e;
        float w0 = pe[i0] / (pe[i0] + pe[i1]);
#pragma unroll
        for (int e = 0; e < NE; e++) logits[(size_t)t * NE + e] = p[e];
        int p0 = atomicAdd(&counts[i0], 1);
        int p1 = atomicAdd(&counts[i1], 1);
        sel[2 * t] = i0;  posn[2 * t] = p0;  wgt[2 * t] = w0;
        sel[2 * t + 1] = i1;  posn[2 * t + 1] = p1;  wgt[2 * t + 1] = 1.f - w0;
    }
}

// ---------------- kernel 3: prefix / tile map ----------------
__global__ void k_prefix(const int* __restrict__ counts, int* __restrict__ base,
                         int* __restrict__ tile_e) {
    if (threadIdx.x == 0) {
        int b = 0, tb = 0;
        for (int e = 0; e < NE; e++) {
            base[e] = b;
            int nt = (counts[e] + BM - 1) / BM;
            for (int i = 0; i < nt; i++) tile_e[tb++] = e;
            b += nt * BM;
        }
        base[NE] = b;
        while (tb < MAXTILES) tile_e[tb++] = -1;
    }
}

// ---------------- kernel 4: gather x -> bf16 compacted rows ----------------
// Pad rows of xg stay 0xAA-poisoned: bf16 0xAAAA = -1.2e-13 (finite, not NaN);
// pad-row outputs are never read by k_combine, so no zeroing needed.
__global__ void k_gather(const float4* __restrict__ x4, const int* __restrict__ sel,
                         const int* __restrict__ posn, const int* __restrict__ base,
                         u16* __restrict__ xg) {
    int p = blockIdx.x;
    int lane = threadIdx.x;       // 64 threads
    int t = p >> 1;
    int row = base[sel[p]] + posn[p];
#pragma unroll
    for (int i = 0; i < 4; i++) {
        int idx = i * 64 + lane;  // float4 index within row (256 per row)
        float4 v = x4[(size_t)t * (H / 4) + idx];
        uint2 o = { cvt2(v.x, v.y), cvt2(v.z, v.w) };
        *(uint2*)&xg[(size_t)row * H + idx * 4] = o;
    }
}

// ---------------- kernel 5: GEMM1  act = silu(x w1^T) * (x w3^T) ----------------
// Pure m97 structure: both A and B tiles staged via global_load_lds x16B.
__global__ __launch_bounds__(256) void k_gemm1(const u16* __restrict__ xg,
                                               const u16* __restrict__ w13b,
                                               u16* __restrict__ act,
                                               const int* __restrict__ tile_e) {
    int e = tile_e[blockIdx.x];
    if (e < 0) return;
    __shared__ u16 As[BM * BK];   // 128x32 bf16, K-contig rows
    __shared__ u16 Bs[BM * BK];   // rows 0-63: w1, rows 64-127: w3

    int tid = threadIdx.x;
    int lane = tid & 63, wave = tid >> 6;
    int quad = lane >> 4, m16 = lane & 15;
    int wm = wave >> 1, wn = wave & 1;
    int row0 = blockIdx.x * BM;
    int n0 = blockIdx.y * 64;
    const u16* wb1 = w13b + ((size_t)e * 2 * FFN + n0) * H;
    const u16* wb3 = w13b + ((size_t)e * 2 * FFN + FFN + n0) * H;

    f32x4 accg[4][2], accu[4][2];
#pragma unroll
    for (int mi = 0; mi < 4; mi++)
#pragma unroll
        for (int ni = 0; ni < 2; ni++) { accg[mi][ni] = {0.f,0.f,0.f,0.f}; accu[mi][ni] = {0.f,0.f,0.f,0.f}; }

    int r4 = tid >> 2, c8 = (tid & 3) * 8;   // 64 rows x 4 chunks per 256 threads
    for (int kk = 0; kk < H; kk += BK) {
        // A tile: 512 chunks, 2/thread
        GLD16(xg + (size_t)(row0 + r4) * H + kk + c8, As + tid * 8);
        GLD16(xg + (size_t)(row0 + 64 + r4) * H + kk + c8, As + 2048 + tid * 8);
        // B tile: w1 rows 0-63, w3 rows 64-127
        GLD16(wb1 + (size_t)r4 * H + kk + c8, Bs + tid * 8);
        GLD16(wb3 + (size_t)r4 * H + kk + c8, Bs + 2048 + tid * 8);
        __syncthreads();
        bf16x8 a[4], bg[2], bu[2];
#pragma unroll
        for (int mi = 0; mi < 4; mi++)
            a[mi] = *(const bf16x8*)&As[(wm * 64 + mi * 16 + m16) * BK + quad * 8];
#pragma unroll
        for (int ni = 0; ni < 2; ni++) {
            bg[ni] = *(const bf16x8*)&Bs[(wn * 32 + ni * 16 + m16) * BK + quad * 8];
            bu[ni] = *(const bf16x8*)&Bs[2048 + (wn * 32 + ni * 16 + m16) * BK + quad * 8];
        }
#pragma unroll
        for (int mi = 0; mi < 4; mi++)
#pragma unroll
            for (int ni = 0; ni < 2; ni++) {
                accg[mi][ni] = __builtin_amdgcn_mfma_f32_16x16x32_bf16(a[mi], bg[ni], accg[mi][ni], 0, 0, 0);
                accu[mi][ni] = __builtin_amdgcn_mfma_f32_16x16x32_bf16(a[mi], bu[ni], accu[mi][ni], 0, 0, 0);
            }
        __syncthreads();
    }
    // epilogue: silu(g)*u -> bf16 act
#pragma unroll
    for (int mi = 0; mi < 4; mi++)
#pragma unroll
        for (int ni = 0; ni < 2; ni++) {
            int gcol = n0 + wn * 32 + ni * 16 + m16;
            int grow = row0 + wm * 64 + mi * 16 + quad * 4;
#pragma unroll
            for (int r = 0; r < 4; r++) {
                float g = accg[mi][ni][r], u = accu[mi][ni][r];
                float hv = g * (1.f / (1.f + __expf(-g))) * u;
                unsigned pk = cvt2(hv, hv);
                act[(size_t)(grow + r) * FFN + gcol] = (u16)(pk & 0xffff);
            }
        }
}

// ---------------- kernel 6: GEMM2  yc = act w2^T  (split-K = 2) ----------------
__global__ __launch_bounds__(256) void k_gemm2(const u16* __restrict__ act,
                                               const u16* __restrict__ w2b,
                                               float* __restrict__ yc,
                                               const int* __restrict__ tile_e) {
    int e = tile_e[blockIdx.x];
    if (e < 0) return;
    __shared__ u16 As[BM * BK];
    __shared__ u16 Bs[BM * BK];

    int tid = threadIdx.x;
    int lane = tid & 63, wave = tid >> 6;
    int quad = lane >> 4, m16 = lane & 15;
    int wm = wave >> 1, wn = wave & 1;
    int row0 = blockIdx.x * BM;
    int n0 = blockIdx.y * 128;
    int k0 = blockIdx.z * (FFN / 2);
    const u16* wb = w2b + ((size_t)e * H + n0) * FFN;
    float* ycp = yc + (size_t)blockIdx.z * ROWCAP * H;

    f32x4 acc[4][4];
#pragma unroll
    for (int mi = 0; mi < 4; mi++)
#pragma unroll
        for (int ni = 0; ni < 4; ni++) acc[mi][ni] = {0.f,0.f,0.f,0.f};

    int r4 = tid >> 2, c8 = (tid & 3) * 8;
    for (int kk = k0; kk < k0 + FFN / 2; kk += BK) {
        GLD16(act + (size_t)(row0 + r4) * FFN + kk + c8, As + tid * 8);
        GLD16(act + (size_t)(row0 + 64 + r4) * FFN + kk + c8, As + 2048 + tid * 8);
        GLD16(wb + (size_t)r4 * FFN + kk + c8, Bs + tid * 8);
        GLD16(wb + (size_t)(64 + r4) * FFN + kk + c8, Bs + 2048 + tid * 8);
        __syncthreads();
        bf16x8 a[4], b[4];
#pragma unroll
        for (int mi = 0; mi < 4; mi++)
            a[mi] = *(const bf16x8*)&As[(wm * 64 + mi * 16 + m16) * BK + quad * 8];
#pragma unroll
        for (int ni = 0; ni < 4; ni++)
            b[ni] = *(const bf16x8*)&Bs[(wn * 64 + ni * 16 + m16) * BK + quad * 8];
#pragma unroll
        for (int mi = 0; mi < 4; mi++)
#pragma unroll
            for (int ni = 0; ni < 4; ni++)
                acc[mi][ni] = __builtin_amdgcn_mfma_f32_16x16x32_bf16(a[mi], b[ni], acc[mi][ni], 0, 0, 0);
        __syncthreads();
    }
#pragma unroll
    for (int mi = 0; mi < 4; mi++)
#pragma unroll
        for (int ni = 0; ni < 4; ni++)
#pragma unroll
            for (int r = 0; r < 4; r++) {
                int grow = row0 + wm * 64 + mi * 16 + quad * 4 + r;
                int gcol = n0 + wn * 64 + ni * 16 + m16;
                ycp[(size_t)grow * H + gcol] = acc[mi][ni][r];
            }
}

// ---------------- kernel 7: combine (sums split-K partials) ----------------
__global__ void k_combine(const float4* __restrict__ yc4, const int* __restrict__ sel,
                          const int* __restrict__ posn, const int* __restrict__ base,
                          const float* __restrict__ wgt, float4* __restrict__ out4) {
    int t = blockIdx.x;
    int j = threadIdx.x;  // 256, H/4
    int r0 = base[sel[2 * t]] + posn[2 * t];
    int r1 = base[sel[2 * t + 1]] + posn[2 * t + 1];
    float w0 = wgt[2 * t], w1 = wgt[2 * t + 1];
    const size_t P = (size_t)ROWCAP * (H / 4);
    float4 a0 = yc4[(size_t)r0 * (H / 4) + j];
    float4 a1 = yc4[(size_t)r0 * (H / 4) + j + P];
    float4 b0 = yc4[(size_t)r1 * (H / 4) + j];
    float4 b1 = yc4[(size_t)r1 * (H / 4) + j + P];
    float4 o = { w0 * (a0.x + a1.x) + w1 * (b0.x + b1.x),
                 w0 * (a0.y + a1.y) + w1 * (b0.y + b1.y),
                 w0 * (a0.z + a1.z) + w1 * (b0.z + b1.z),
                 w0 * (a0.w + a1.w) + w1 * (b0.w + b1.w) };
    out4[(size_t)t * (H / 4) + j] = o;
}

extern "C" void kernel_launch(void* const* d_in, const int* in_sizes, int n_in,
                              void* d_out, int out_size, void* d_ws, size_t ws_size,
                              hipStream_t stream) {
    const float* x   = (const float*)d_in[0];
    const float* gw  = (const float*)d_in[1];
    const float* w13 = (const float*)d_in[2];
    const float* w2  = (const float*)d_in[3];
    float* out    = (float*)d_out;
    float* logits = out + (size_t)TOK * H;

    char* ws = (char*)d_ws;
    int*   counts = (int*)ws;
    int*   base   = (int*)(ws + 256);
    int*   tile_e = (int*)(ws + 512);
    int*   sel    = (int*)(ws + 1024);
    int*   posn   = (int*)(ws + 1024 + 4 * PAIRS);
    float* wgt    = (float*)(ws + 1024 + 8 * PAIRS);
    u16*   xg     = (u16*)(ws + 65536);                       // 10.5 MB
    u16*   act    = xg + (size_t)ROWCAP * H;                  // 41.9 MB
    u16*   w13b   = act + (size_t)ROWCAP * FFN;               // 134.2 MB
    u16*   w2b    = w13b + (size_t)NE * 2 * FFN * H;          // 67.1 MB
    float* yc     = (float*)w13b;  // overlay: w13b dead after gemm1; yc = 2x20.9 MB

    k_cvtw<<<49152, 256, 0, stream>>>((const float4*)w13, (const float4*)w2,
                                      (uint4*)w13b, (uint4*)w2b);
    k_init<<<1, 64, 0, stream>>>(counts);
    k_router<<<TOK / 4, 256, 0, stream>>>(x, gw, logits, counts, sel, posn, wgt);
    k_prefix<<<1, 64, 0, stream>>>(counts, base, tile_e);
    k_gather<<<PAIRS, 64, 0, stream>>>((const float4*)x, sel, posn, base, xg);
    dim3 g1(MAXTILES, FFN / 64);
    k_gemm1<<<g1, 256, 0, stream>>>(xg, w13b, act, tile_e);
    dim3 g2(MAXTILES, H / 128, 2);
    k_gemm2<<<g2, 256, 0, stream>>>(act, w2b, yc, tile_e);
    k_combine<<<TOK, 256, 0, stream>>>((const float4*)yc, sel, posn, base, wgt, (float4*)out);
}

// Round 5
// 723.067 us; speedup vs baseline: 1.0484x; 1.0484x over previous
//
#include <hip/hip_runtime.h>
#include <hip/hip_bf16.h>
#include <math.h>

#define H     1024
#define FFN   4096
#define NE    8
#define TOK   2048
#define PAIRS (TOK*2)
#define BM    128
#define BK    32
#define ROWCAP (PAIRS + NE*BM)   /* 5120 worst-case padded rows */
#define MAXTILES (ROWCAP/BM)     /* 40 */

typedef unsigned short u16;
typedef __attribute__((ext_vector_type(8))) __bf16 bf16x8;
typedef __attribute__((ext_vector_type(4))) float  f32x4;

// hardware v_cvt_pk_bf16_f32: 2 floats -> packed 2xbf16 in one inst
__device__ __forceinline__ unsigned cvt2(float a, float b) {
    __hip_bfloat162 h = __float22bfloat162_rn(float2{a, b});
    unsigned u;
    __builtin_memcpy(&u, &h, 4);
    return u;
}

// pack 8 fp32 (two float4s, K-order) -> bf16x8 fragment
__device__ __forceinline__ bf16x8 pack8(float4 f0, float4 f1) {
    uint4 p = { cvt2(f0.x, f0.y), cvt2(f0.z, f0.w),
                cvt2(f1.x, f1.y), cvt2(f1.z, f1.w) };
    bf16x8 r;
    __builtin_memcpy(&r, &p, 16);
    return r;
}

#define GLD16(gp, lp) __builtin_amdgcn_global_load_lds( \
    (const __attribute__((address_space(1))) void*)(gp), \
    (__attribute__((address_space(3))) void*)(lp), 16, 0, 0)

// ---------------- kernel 1: init counts ----------------
__global__ void k_init(int* counts) {
    if (threadIdx.x < NE) counts[threadIdx.x] = 0;
}

// ---------------- kernel 2: router ----------------
__global__ void k_router(const float* __restrict__ x, const float* __restrict__ gw,
                         float* __restrict__ logits, int* counts,
                         int* __restrict__ sel, int* __restrict__ posn, float* __restrict__ wgt) {
    int lane = threadIdx.x & 63;
    int t = blockIdx.x * 4 + (threadIdx.x >> 6);
    float p[NE];
#pragma unroll
    for (int e = 0; e < NE; e++) p[e] = 0.f;
    for (int j = 0; j < H / 64; j++) {
        int h = lane + j * 64;
        float xv = x[(size_t)t * H + h];
#pragma unroll
        for (int e = 0; e < NE; e++) p[e] = fmaf(xv, gw[e * H + h], p[e]);
    }
#pragma unroll
    for (int off = 32; off; off >>= 1)
#pragma unroll
        for (int e = 0; e < NE; e++) p[e] += __shfl_xor(p[e], off, 64);
    if (lane == 0) {
        float mx = p[0];
#pragma unroll
        for (int e = 1; e < NE; e++) mx = fmaxf(mx, p[e]);
        float pe[NE];
#pragma unroll
        for (int e = 0; e < NE; e++) pe[e] = __expf(p[e] - mx);
        int i0 = 0;
#pragma unroll
        for (int e = 1; e < NE; e++) if (pe[e] > pe[i0]) i0 = e;
        int i1 = (i0 == 0) ? 1 : 0;
#pragma unroll
        for (int e = 0; e < NE; e++) if (e != i1 && e != i0 && pe[e] > pe[i1]) i1 = e;
        float w0 = pe[i0] / (pe[i0] + pe[i1]);
#pragma unroll
        for (int e = 0; e < NE; e++) logits[(size_t)t * NE + e] = p[e];
        int p0 = atomicAdd(&counts[i0], 1);
        int p1 = atomicAdd(&counts[i1], 1);
        sel[2 * t] = i0;  posn[2 * t] = p0;  wgt[2 * t] = w0;
        sel[2 * t + 1] = i1;  posn[2 * t + 1] = p1;  wgt[2 * t + 1] = 1.f - w0;
    }
}

// ---------------- kernel 3: prefix / tile map ----------------
__global__ void k_prefix(const int* __restrict__ counts, int* __restrict__ base,
                         int* __restrict__ tile_e) {
    if (threadIdx.x == 0) {
        int b = 0, tb = 0;
        for (int e = 0; e < NE; e++) {
            base[e] = b;
            int nt = (counts[e] + BM - 1) / BM;
            for (int i = 0; i < nt; i++) tile_e[tb++] = e;
            b += nt * BM;
        }
        base[NE] = b;
        while (tb < MAXTILES) tile_e[tb++] = -1;
    }
}

// ---------------- kernel 4: gather x -> bf16 compacted rows ----------------
// Pad rows of xg stay 0xAA-poisoned: bf16 0xAAAA = -1.2e-13 (finite, not NaN);
// pad-row outputs are never read by k_combine, so no zeroing needed.
__global__ void k_gather(const float4* __restrict__ x4, const int* __restrict__ sel,
                         const int* __restrict__ posn, const int* __restrict__ base,
                         u16* __restrict__ xg) {
    int p = blockIdx.x;
    int lane = threadIdx.x;       // 64 threads
    int t = p >> 1;
    int row = base[sel[p]] + posn[p];
#pragma unroll
    for (int i = 0; i < 4; i++) {
        int idx = i * 64 + lane;  // float4 index within row (256 per row)
        float4 v = x4[(size_t)t * (H / 4) + idx];
        uint2 o = { cvt2(v.x, v.y), cvt2(v.z, v.w) };
        *(uint2*)&xg[(size_t)row * H + idx * 4] = o;
    }
}

// ---------------- kernel 5: GEMM1  act = silu(x w1^T) * (x w3^T) ----------------
// A (bf16) + B (fp32, XOR-swizzled) both staged via global_load_lds x16B.
// fp32->bf16 conversion happens on the LDS->register fragment path.
__global__ __launch_bounds__(256) void k_gemm1(const u16* __restrict__ xg,
                                               const float* __restrict__ w13,
                                               u16* __restrict__ act,
                                               const int* __restrict__ tile_e) {
    int e = tile_e[blockIdx.x];
    if (e < 0) return;
    __shared__ alignas(16) u16   As[BM * BK];   // 128x32 bf16, unswizzled (b128 reads already at bank floor)
    __shared__ alignas(16) float Bs1[64 * BK];  // w1 rows; chunk slot s holds global chunk s^(r&7)
    __shared__ alignas(16) float Bs3[64 * BK];  // w3 rows; same swizzle

    int tid = threadIdx.x;
    int lane = tid & 63, wave = tid >> 6;
    int quad = lane >> 4, m16 = lane & 15;
    int wm = wave >> 1, wn = wave & 1;
    int row0 = blockIdx.x * BM;
    int n0 = blockIdx.y * 64;
    const u16*   xb  = xg + (size_t)row0 * H;
    const float* wb1 = w13 + ((size_t)e * 2 * FFN + n0) * H;
    const float* wb3 = w13 + ((size_t)e * 2 * FFN + FFN + n0) * H;

    f32x4 accg[4][2], accu[4][2];
#pragma unroll
    for (int mi = 0; mi < 4; mi++)
#pragma unroll
        for (int ni = 0; ni < 2; ni++) { accg[mi][ni] = {0.f,0.f,0.f,0.f}; accu[mi][ni] = {0.f,0.f,0.f,0.f}; }

    // staging index precompute
    int ra0 = tid >> 2,        ca0 = (tid & 3) * 8;                 // A chunk 0 (unswizzled)
    int ra1 = (256 + tid) >> 2, ca1 = ((256 + tid) & 3) * 8;        // A chunk 1
    int rb0 = tid >> 3,        sb0 = tid & 7;                       // B slots
    int cb0 = (sb0 ^ (rb0 & 7)) * 4;
    int rb1 = (256 + tid) >> 3, sb1 = (256 + tid) & 7;
    int cb1 = (sb1 ^ (rb1 & 7)) * 4;

    for (int kk = 0; kk < H; kk += BK) {
        GLD16(xb + (size_t)ra0 * H + kk + ca0, As + tid * 8);
        GLD16(xb + (size_t)ra1 * H + kk + ca1, As + 2048 + tid * 8);
        GLD16(wb1 + (size_t)rb0 * H + kk + cb0, Bs1 + tid * 4);
        GLD16(wb1 + (size_t)rb1 * H + kk + cb1, Bs1 + 1024 + tid * 4);
        GLD16(wb3 + (size_t)rb0 * H + kk + cb0, Bs3 + tid * 4);
        GLD16(wb3 + (size_t)rb1 * H + kk + cb1, Bs3 + 1024 + tid * 4);
        __syncthreads();
        bf16x8 a[4], bg[2], bu[2];
#pragma unroll
        for (int mi = 0; mi < 4; mi++)
            a[mi] = *(const bf16x8*)&As[(wm * 64 + mi * 16 + m16) * BK + quad * 8];
#pragma unroll
        for (int ni = 0; ni < 2; ni++) {
            int r = wn * 32 + ni * 16 + m16;
            int s0 = ((2 * quad) ^ (r & 7)) * 4, s1 = ((2 * quad + 1) ^ (r & 7)) * 4;
            float4 f0 = *(const float4*)&Bs1[r * BK + s0];
            float4 f1 = *(const float4*)&Bs1[r * BK + s1];
            bg[ni] = pack8(f0, f1);
            float4 g0 = *(const float4*)&Bs3[r * BK + s0];
            float4 g1 = *(const float4*)&Bs3[r * BK + s1];
            bu[ni] = pack8(g0, g1);
        }
#pragma unroll
        for (int mi = 0; mi < 4; mi++)
#pragma unroll
            for (int ni = 0; ni < 2; ni++) {
                accg[mi][ni] = __builtin_amdgcn_mfma_f32_16x16x32_bf16(a[mi], bg[ni], accg[mi][ni], 0, 0, 0);
                accu[mi][ni] = __builtin_amdgcn_mfma_f32_16x16x32_bf16(a[mi], bu[ni], accu[mi][ni], 0, 0, 0);
            }
        __syncthreads();
    }
    // epilogue: silu(g)*u -> bf16 act
#pragma unroll
    for (int mi = 0; mi < 4; mi++)
#pragma unroll
        for (int ni = 0; ni < 2; ni++) {
            int gcol = n0 + wn * 32 + ni * 16 + m16;
            int grow = row0 + wm * 64 + mi * 16 + quad * 4;
#pragma unroll
            for (int r = 0; r < 4; r++) {
                float g = accg[mi][ni][r], u = accu[mi][ni][r];
                float hv = g * (1.f / (1.f + __expf(-g))) * u;
                unsigned pk = cvt2(hv, hv);
                act[(size_t)(grow + r) * FFN + gcol] = (u16)(pk & 0xffff);
            }
        }
}

// ---------------- kernel 6: GEMM2  yc = act w2^T  (split-K = 2) ----------------
__global__ __launch_bounds__(256) void k_gemm2(const u16* __restrict__ act,
                                               const float* __restrict__ w2,
                                               float* __restrict__ yc,
                                               const int* __restrict__ tile_e) {
    int e = tile_e[blockIdx.x];
    if (e < 0) return;
    __shared__ alignas(16) u16   As[BM * BK];
    __shared__ alignas(16) float Bs[BM * BK];   // w2 rows (H-dim), swizzled s^(r&7)

    int tid = threadIdx.x;
    int lane = tid & 63, wave = tid >> 6;
    int quad = lane >> 4, m16 = lane & 15;
    int wm = wave >> 1, wn = wave & 1;
    int row0 = blockIdx.x * BM;
    int n0 = blockIdx.y * 128;
    int k0 = blockIdx.z * (FFN / 2);
    const u16*   ab = act + (size_t)row0 * FFN;
    const float* wb = w2 + ((size_t)e * H + n0) * FFN;
    float* ycp = yc + (size_t)blockIdx.z * ROWCAP * H;

    f32x4 acc[4][4];
#pragma unroll
    for (int mi = 0; mi < 4; mi++)
#pragma unroll
        for (int ni = 0; ni < 4; ni++) acc[mi][ni] = {0.f,0.f,0.f,0.f};

    int ra0 = tid >> 2,         ca0 = (tid & 3) * 8;
    int ra1 = (256 + tid) >> 2, ca1 = ((256 + tid) & 3) * 8;

    for (int kk = k0; kk < k0 + FFN / 2; kk += BK) {
        GLD16(ab + (size_t)ra0 * FFN + kk + ca0, As + tid * 8);
        GLD16(ab + (size_t)ra1 * FFN + kk + ca1, As + 2048 + tid * 8);
#pragma unroll
        for (int i = 0; i < 4; i++) {
            int l = i * 256 + tid;
            int r = l >> 3, s = l & 7;
            int c = (s ^ (r & 7)) * 4;
            GLD16(wb + (size_t)r * FFN + kk + c, Bs + l * 4);
        }
        __syncthreads();
        bf16x8 a[4], b[4];
#pragma unroll
        for (int mi = 0; mi < 4; mi++)
            a[mi] = *(const bf16x8*)&As[(wm * 64 + mi * 16 + m16) * BK + quad * 8];
#pragma unroll
        for (int ni = 0; ni < 4; ni++) {
            int r = wn * 64 + ni * 16 + m16;
            int s0 = ((2 * quad) ^ (r & 7)) * 4, s1 = ((2 * quad + 1) ^ (r & 7)) * 4;
            float4 f0 = *(const float4*)&Bs[r * BK + s0];
            float4 f1 = *(const float4*)&Bs[r * BK + s1];
            b[ni] = pack8(f0, f1);
        }
#pragma unroll
        for (int mi = 0; mi < 4; mi++)
#pragma unroll
            for (int ni = 0; ni < 4; ni++)
                acc[mi][ni] = __builtin_amdgcn_mfma_f32_16x16x32_bf16(a[mi], b[ni], acc[mi][ni], 0, 0, 0);
        __syncthreads();
    }
#pragma unroll
    for (int mi = 0; mi < 4; mi++)
#pragma unroll
        for (int ni = 0; ni < 4; ni++)
#pragma unroll
            for (int r = 0; r < 4; r++) {
                int grow = row0 + wm * 64 + mi * 16 + quad * 4 + r;
                int gcol = n0 + wn * 64 + ni * 16 + m16;
                ycp[(size_t)grow * H + gcol] = acc[mi][ni][r];
            }
}

// ---------------- kernel 7: combine (sums split-K partials) ----------------
__global__ void k_combine(const float4* __restrict__ yc4, const int* __restrict__ sel,
                          const int* __restrict__ posn, const int* __restrict__ base,
                          const float* __restrict__ wgt, float4* __restrict__ out4) {
    int t = blockIdx.x;
    int j = threadIdx.x;  // 256, H/4
    int r0 = base[sel[2 * t]] + posn[2 * t];
    int r1 = base[sel[2 * t + 1]] + posn[2 * t + 1];
    float w0 = wgt[2 * t], w1 = wgt[2 * t + 1];
    const size_t P = (size_t)ROWCAP * (H / 4);
    float4 a0 = yc4[(size_t)r0 * (H / 4) + j];
    float4 a1 = yc4[(size_t)r0 * (H / 4) + j + P];
    float4 b0 = yc4[(size_t)r1 * (H / 4) + j];
    float4 b1 = yc4[(size_t)r1 * (H / 4) + j + P];
    float4 o = { w0 * (a0.x + a1.x) + w1 * (b0.x + b1.x),
                 w0 * (a0.y + a1.y) + w1 * (b0.y + b1.y),
                 w0 * (a0.z + a1.z) + w1 * (b0.z + b1.z),
                 w0 * (a0.w + a1.w) + w1 * (b0.w + b1.w) };
    out4[(size_t)t * (H / 4) + j] = o;
}

extern "C" void kernel_launch(void* const* d_in, const int* in_sizes, int n_in,
                              void* d_out, int out_size, void* d_ws, size_t ws_size,
                              hipStream_t stream) {
    const float* x   = (const float*)d_in[0];
    const float* gw  = (const float*)d_in[1];
    const float* w13 = (const float*)d_in[2];
    const float* w2  = (const float*)d_in[3];
    float* out    = (float*)d_out;
    float* logits = out + (size_t)TOK * H;

    char* ws = (char*)d_ws;
    int*   counts = (int*)ws;
    int*   base   = (int*)(ws + 256);
    int*   tile_e = (int*)(ws + 512);
    int*   sel    = (int*)(ws + 1024);
    int*   posn   = (int*)(ws + 1024 + 4 * PAIRS);
    float* wgt    = (float*)(ws + 1024 + 8 * PAIRS);
    u16*   xg     = (u16*)(ws + 65536);                       // 10.5 MB
    u16*   act    = xg + (size_t)ROWCAP * H;                  // 41.9 MB
    float* yc     = (float*)(act + (size_t)ROWCAP * FFN);     // 2 x 20.9 MB split-K partials

    k_init<<<1, 64, 0, stream>>>(counts);
    k_router<<<TOK / 4, 256, 0, stream>>>(x, gw, logits, counts, sel, posn, wgt);
    k_prefix<<<1, 64, 0, stream>>>(counts, base, tile_e);
    k_gather<<<PAIRS, 64, 0, stream>>>((const float4*)x, sel, posn, base, xg);
    dim3 g1(MAXTILES, FFN / 64);
    k_gemm1<<<g1, 256, 0, stream>>>(xg, w13, act, tile_e);
    dim3 g2(MAXTILES, H / 128, 2);
    k_gemm2<<<g2, 256, 0, stream>>>(act, w2, yc, tile_e);
    k_combine<<<TOK, 256, 0, stream>>>((const float4*)yc, sel, posn, base, wgt, (float4*)out);
}